// Round 1
// baseline (3521.064 us; speedup 1.0000x reference)
//
#include <hip/hip_runtime.h>

namespace {
constexpr int B = 4, C = 64, H = 512, W = 512;
constexpr int HW = H * W;
constexpr float EPS = 1e-5f;

__global__ __launch_bounds__(256) void init_aa_kernel(float* __restrict__ aa) {
    int i = blockIdx.x * 256 + threadIdx.x;
    aa[i] = EPS;
}

__global__ __launch_bounds__(256) void conv_scatter_kernel(
    const float* __restrict__ x, const float* __restrict__ wmat,
    const float* __restrict__ bias, float* __restrict__ out,
    float* __restrict__ offset, float* __restrict__ dest,
    float* __restrict__ aa)
{
    __shared__ float wsh[3 * C];
    int t = threadIdx.x;
    if (t < 3 * C) wsh[t] = wmat[t];
    __syncthreads();

    int gid = blockIdx.x * 256 + t;       // pixel id within B*HW (grid exact)
    int b = gid >> 18;                    // / HW  (HW = 2^18)
    int p = gid & (HW - 1);
    int hh = p >> 9, ww = p & (W - 1);

    const float* xb = x + (size_t)b * C * HW + p;
    float xv[C];
    float acc0 = 0.f, acc1 = 0.f, acc2 = 0.f;
#pragma unroll
    for (int c = 0; c < C; ++c) {
        float v = xb[(size_t)c * HW];     // coalesced across lanes per c
        xv[c] = v;
        acc0 = fmaf(v, wsh[c], acc0);
        acc1 = fmaf(v, wsh[C + c], acc1);
        acc2 = fmaf(v, wsh[2 * C + c], acc2);
    }
    acc0 += bias[0];
    acc1 += bias[1];
    acc2 += bias[2];

    float off_y = acc0 * (float)H;        // DOWNSAMPLE = 1.0 -> ds_h = H
    float off_x = acc1 * (float)W;
    float att = expf(acc2);

    int dy = (int)rintf((float)hh + off_y);   // rintf = round-half-to-even, same as jnp.round
    dy = min(max(dy, 0), H - 1);
    int dx = (int)rintf((float)ww + off_x);
    dx = min(max(dx, 0), W - 1);
    int idx = dy * W + dx;

    size_t ob = (size_t)b * 2 * HW;
    offset[ob + p]      = off_y;
    offset[ob + HW + p] = off_x;
    dest[ob + p]      = (float)dy;        // small ints, exact in f32
    dest[ob + HW + p] = (float)dx;

    atomicAdd(&aa[b * HW + idx], att);
    float* outp = out + (size_t)b * C * HW + idx;
#pragma unroll
    for (int c = 0; c < C; ++c) {
        atomicAdd(&outp[(size_t)c * HW], xv[c] * att);
    }
}

__global__ __launch_bounds__(256) void normalize_kernel(
    float* __restrict__ out, const float* __restrict__ aa)
{
    int i4 = blockIdx.x * 256 + threadIdx.x;  // float4 index (grid exact)
    size_t e = (size_t)i4 * 4;
    int b = (int)(e / ((size_t)C * HW));
    int p = (int)(e & (size_t)(HW - 1));      // element within plane; 4 | HW
    float4 v = *reinterpret_cast<float4*>(out + e);
    const float4 a = *reinterpret_cast<const float4*>(aa + (size_t)b * HW + p);
    v.x /= a.x; v.y /= a.y; v.z /= a.z; v.w /= a.w;
    *reinterpret_cast<float4*>(out + e) = v;
}
} // namespace

extern "C" void kernel_launch(void* const* d_in, const int* in_sizes, int n_in,
                              void* d_out, int out_size, void* d_ws, size_t ws_size,
                              hipStream_t stream) {
    const float* x    = (const float*)d_in[0];
    const float* wmat = (const float*)d_in[1];
    const float* bias = (const float*)d_in[2];

    float* out    = (float*)d_out;                    // [B,C,H,W]
    float* offset = out + (size_t)B * C * HW;         // [B,2,H,W]
    float* dest   = offset + (size_t)B * 2 * HW;      // [B,2,H,W] (ints as f32)
    float* aa     = (float*)d_ws;                     // [B,HW]

    hipMemsetAsync(out, 0, (size_t)B * C * HW * sizeof(float), stream);
    init_aa_kernel<<<B * HW / 256, 256, 0, stream>>>(aa);
    conv_scatter_kernel<<<B * HW / 256, 256, 0, stream>>>(x, wmat, bias, out, offset, dest, aa);
    normalize_kernel<<<(B * (size_t)C * HW / 4) / 256, 256, 0, stream>>>(out, aa);
}